// Round 1
// baseline (786.388 us; speedup 1.0000x reference)
//
#include <hip/hip_runtime.h>
#include <hip/hip_bf16.h>
#include <stdint.h>

// Problem constants (QuantizedLinear: x[8,512,4096] fp32, W[11008,4096] int8-in-int32, scale[11008] fp32)
#define M_DIM 4096
#define N_DIM 11008
#define K_DIM 4096

typedef __bf16 bf16x8 __attribute__((ext_vector_type(8)));
typedef float f32x4 __attribute__((ext_vector_type(4)));

// fp32 -> bf16 round-to-nearest-even (bit-level; exact for small ints)
static __device__ __forceinline__ uint16_t f32_to_bf16(float f) {
    union { float f; uint32_t u; } v; v.f = f;
    uint32_t u = v.u;
    u += 0x7FFFu + ((u >> 16) & 1u);
    return (uint16_t)(u >> 16);
}

// async global->LDS, 16 bytes/lane. LDS dest = wave-uniform base + lane*16.
static __device__ __forceinline__ void direct_load16(const void* gptr, void* ldsptr) {
    __builtin_amdgcn_global_load_lds(
        (const __attribute__((address_space(1))) void*)gptr,
        (__attribute__((address_space(3))) void*)ldsptr,
        16, 0, 0);
}

// ---- conversion kernels --------------------------------------------------

// W: int32 (values in [-127,127]) -> bf16, 8 elems/thread
__global__ void cvt_w_kernel(const int* __restrict__ w, uint16_t* __restrict__ o) {
    int t = blockIdx.x * 256 + threadIdx.x;
    const int4* w4 = (const int4*)w;
    int4 a = w4[2 * t];
    int4 b = w4[2 * t + 1];
    union { uint16_t h[8]; uint4 v; } r;
    r.h[0] = f32_to_bf16((float)a.x);
    r.h[1] = f32_to_bf16((float)a.y);
    r.h[2] = f32_to_bf16((float)a.z);
    r.h[3] = f32_to_bf16((float)a.w);
    r.h[4] = f32_to_bf16((float)b.x);
    r.h[5] = f32_to_bf16((float)b.y);
    r.h[6] = f32_to_bf16((float)b.z);
    r.h[7] = f32_to_bf16((float)b.w);
    ((uint4*)o)[t] = r.v;
}

// x: fp32 -> bf16, 8 elems/thread
__global__ void cvt_x_kernel(const float* __restrict__ x, uint16_t* __restrict__ o) {
    int t = blockIdx.x * 256 + threadIdx.x;
    const float4* x4 = (const float4*)x;
    float4 a = x4[2 * t];
    float4 b = x4[2 * t + 1];
    union { uint16_t h[8]; uint4 v; } r;
    r.h[0] = f32_to_bf16(a.x);
    r.h[1] = f32_to_bf16(a.y);
    r.h[2] = f32_to_bf16(a.z);
    r.h[3] = f32_to_bf16(a.w);
    r.h[4] = f32_to_bf16(b.x);
    r.h[5] = f32_to_bf16(b.y);
    r.h[6] = f32_to_bf16(b.z);
    r.h[7] = f32_to_bf16(b.w);
    ((uint4*)o)[t] = r.v;
}

// ---- GEMM: C[M][N] = A[M][K] * B[N][K]^T, epilogue *scale[n] -------------
// 128x128 tile, BK=32, 256 threads = 4 waves (2x2), wave does 4x4 of 16x16x32 MFMA.

__global__ __launch_bounds__(256) void gemm_bt_kernel(
    const uint16_t* __restrict__ A,   // [M][K] bf16
    const uint16_t* __restrict__ B,   // [N][K] bf16
    const float* __restrict__ scale,  // [N]
    float* __restrict__ C)            // [M][N]
{
    __shared__ uint16_t As[128 * 32];  // row-major [128][32], unpadded (global_load_lds layout)
    __shared__ uint16_t Bs[128 * 32];

    const int tid  = threadIdx.x;
    const int lane = tid & 63;
    const int wave = tid >> 6;
    const int wm   = wave >> 1;        // wave row (0..1) -> 64 rows
    const int wn   = wave & 1;         // wave col (0..1) -> 64 cols
    const int quad = lane >> 4;        // 0..3
    const int r16  = lane & 15;        // 0..15

    const int m0 = blockIdx.x * 128;   // m-tile fastest -> consecutive blocks share B tile in L2
    const int n0 = blockIdx.y * 128;

    // staging source addrs: thread t loads row (t>>2), cols (t&3)*8 .. +8 (16B)
    const int lrow = tid >> 2;         // 0..63
    const int lcol = (tid & 3) * 8;
    const uint16_t* ga0 = A + (size_t)(m0 + lrow) * K_DIM + lcol;
    const uint16_t* ga1 = A + (size_t)(m0 + 64 + lrow) * K_DIM + lcol;
    const uint16_t* gb0 = B + (size_t)(n0 + lrow) * K_DIM + lcol;
    const uint16_t* gb1 = B + (size_t)(n0 + 64 + lrow) * K_DIM + lcol;

    char* lAs = (char*)As;
    char* lBs = (char*)Bs;
    const int wb = wave * 1024;        // per-wave LDS slice (64 lanes * 16B)

    f32x4 acc[4][4];
#pragma unroll
    for (int i = 0; i < 4; i++)
#pragma unroll
        for (int j = 0; j < 4; j++) acc[i][j] = (f32x4)(0.0f);

    for (int k0 = 0; k0 < K_DIM; k0 += 32) {
        direct_load16(ga0, lAs + wb);
        direct_load16(ga1, lAs + 4096 + wb);
        direct_load16(gb0, lBs + wb);
        direct_load16(gb1, lBs + 4096 + wb);
        ga0 += 32; ga1 += 32; gb0 += 32; gb1 += 32;
        __syncthreads();   // drains vmcnt -> staged data visible

        bf16x8 af[4], bf[4];
#pragma unroll
        for (int i = 0; i < 4; i++)
            af[i] = *(const bf16x8*)&As[(wm * 64 + i * 16 + r16) * 32 + quad * 8];
#pragma unroll
        for (int j = 0; j < 4; j++)
            bf[j] = *(const bf16x8*)&Bs[(wn * 64 + j * 16 + r16) * 32 + quad * 8];

#pragma unroll
        for (int i = 0; i < 4; i++)
#pragma unroll
            for (int j = 0; j < 4; j++)
                acc[i][j] = __builtin_amdgcn_mfma_f32_16x16x32_bf16(af[i], bf[j], acc[i][j], 0, 0, 0);

        __syncthreads();   // all waves done reading LDS before next overwrite
    }

    // epilogue: apply per-output-channel scale, store fp32
#pragma unroll
    for (int j = 0; j < 4; j++) {
        const int n = n0 + wn * 64 + j * 16 + r16;
        const float s = scale[n];
#pragma unroll
        for (int i = 0; i < 4; i++) {
            const int mrow = m0 + wm * 64 + i * 16 + quad * 4;
#pragma unroll
            for (int r = 0; r < 4; r++)
                C[(size_t)(mrow + r) * N_DIM + n] = acc[i][j][r] * s;
        }
    }
}

// ---- launcher ------------------------------------------------------------

extern "C" void kernel_launch(void* const* d_in, const int* in_sizes, int n_in,
                              void* d_out, int out_size, void* d_ws, size_t ws_size,
                              hipStream_t stream) {
    const float* x        = (const float*)d_in[0];   // [4096][4096]
    const int*   w_int    = (const int*)d_in[1];     // [11008][4096]
    const float* w_scale  = (const float*)d_in[2];   // [11008]
    float*       out      = (float*)d_out;           // [4096][11008]

    // workspace layout: W_bf16 (90,177,536 B) | X_bf16 (33,554,432 B)
    uint16_t* wb = (uint16_t*)d_ws;
    uint16_t* xb = (uint16_t*)((char*)d_ws + (size_t)N_DIM * K_DIM * 2);

    // W: 45,088,768 elems / 8 per thread / 256 per block = 22016 blocks
    cvt_w_kernel<<<dim3(22016), dim3(256), 0, stream>>>(w_int, wb);
    // x: 16,777,216 elems / 8 / 256 = 8192 blocks
    cvt_x_kernel<<<dim3(8192), dim3(256), 0, stream>>>(x, xb);

    // GEMM: grid (M/128, N/128) = (32, 86)
    gemm_bt_kernel<<<dim3(M_DIM / 128, N_DIM / 128), dim3(256), 0, stream>>>(xb, wb, w_scale, out);
}

// Round 2
// 619.283 us; speedup vs baseline: 1.2698x; 1.2698x over previous
//
#include <hip/hip_runtime.h>
#include <hip/hip_bf16.h>
#include <stdint.h>

// QuantizedLinear: x[8,512,4096] fp32, W[11008,4096] int8-in-int32, scale[11008] fp32
#define M_DIM 4096
#define N_DIM 11008
#define K_DIM 4096

typedef int   i32x4 __attribute__((ext_vector_type(4)));

// async global->LDS, 16 bytes/lane. LDS dest = wave-uniform base + lane*16.
static __device__ __forceinline__ void direct_load16(const void* gptr, void* ldsptr) {
    __builtin_amdgcn_global_load_lds(
        (const __attribute__((address_space(1))) void*)gptr,
        (__attribute__((address_space(3))) void*)ldsptr,
        16, 0, 0);
}

// ---- W: int32 in [-127,127] -> int8, 8 elems/thread, coalesced ----------
__global__ __launch_bounds__(256) void cvt_w_kernel(const int* __restrict__ w,
                                                    int8_t* __restrict__ o) {
    int t = blockIdx.x * 256 + threadIdx.x;
    const int4* w4 = (const int4*)w;
    int4 a = w4[2 * t];
    int4 b = w4[2 * t + 1];
    uint2 r;
    r.x = (a.x & 255) | ((a.y & 255) << 8) | ((a.z & 255) << 16) | (a.w << 24);
    r.y = (b.x & 255) | ((b.y & 255) << 8) | ((b.z & 255) << 16) | (b.w << 24);
    ((uint2*)o)[t] = r;
}

// ---- x: fp32 -> int8 with per-row absmax scale --------------------------
// one block per row (4096 rows x 4096 cols); 256 threads x 16 elems
__global__ __launch_bounds__(256) void quant_x_kernel(const float* __restrict__ x,
                                                      int8_t* __restrict__ xq,
                                                      float* __restrict__ xs) {
    __shared__ float wmax[4];
    const int row = blockIdx.x;
    const int t = threadIdx.x;
    const float4* xr = (const float4*)(x + (size_t)row * K_DIM);

    float4 v[4];
    float am = 0.0f;
#pragma unroll
    for (int p = 0; p < 4; p++) {
        v[p] = xr[p * 256 + t];
        am = fmaxf(am, fmaxf(fmaxf(fabsf(v[p].x), fabsf(v[p].y)),
                             fmaxf(fabsf(v[p].z), fabsf(v[p].w))));
    }
    // wave reduce (64 lanes)
#pragma unroll
    for (int o = 32; o > 0; o >>= 1)
        am = fmaxf(am, __shfl_xor(am, o));
    if ((t & 63) == 0) wmax[t >> 6] = am;
    __syncthreads();
    am = fmaxf(fmaxf(wmax[0], wmax[1]), fmaxf(wmax[2], wmax[3]));

    const float inv = 127.0f / am;
    int* oq = (int*)(xq + (size_t)row * K_DIM);
#pragma unroll
    for (int p = 0; p < 4; p++) {
        int qa = (int)rintf(v[p].x * inv);
        int qb = (int)rintf(v[p].y * inv);
        int qc = (int)rintf(v[p].z * inv);
        int qd = (int)rintf(v[p].w * inv);
        oq[p * 256 + t] = (qa & 255) | ((qb & 255) << 8) | ((qc & 255) << 16) | (qd << 24);
    }
    if (t == 0) xs[row] = am * (1.0f / 127.0f);
}

// ---- GEMM: C[M][N] = (Aq[M][K] . Bq[N][K]^T) * xs[m] * ws[n] ------------
// 128x128 tile, BK=64 int8 (64 B/row — same bytes/iter as bf16 BK=32),
// 256 threads = 4 waves (2x2), wave does 4x4 of mfma_i32_16x16x64_i8.

__global__ __launch_bounds__(256) void gemm_i8_kernel(
    const int8_t* __restrict__ A,     // [M][K] i8
    const int8_t* __restrict__ B,     // [N][K] i8
    const float* __restrict__ xs,     // [M] row scales (absmax/127)
    const float* __restrict__ ws,     // [N] weight scales
    float* __restrict__ C)            // [M][N] fp32
{
    __shared__ int8_t As[128 * 64];   // [128][64] unpadded (global_load_lds layout)
    __shared__ int8_t Bs[128 * 64];

    const int tid  = threadIdx.x;
    const int lane = tid & 63;
    const int wave = tid >> 6;
    const int wm   = wave >> 1;
    const int wn   = wave & 1;
    const int quad = lane >> 4;
    const int r16  = lane & 15;

    const int m0 = blockIdx.x * 128;  // m fastest -> consecutive blocks share B tile in L2
    const int n0 = blockIdx.y * 128;

    // staging: thread t -> row t>>2 (and +64), byte col (t&3)*16
    const int lrow = tid >> 2;
    const int lcol = (tid & 3) * 16;
    const int8_t* ga0 = A + (size_t)(m0 + lrow) * K_DIM + lcol;
    const int8_t* ga1 = A + (size_t)(m0 + 64 + lrow) * K_DIM + lcol;
    const int8_t* gb0 = B + (size_t)(n0 + lrow) * K_DIM + lcol;
    const int8_t* gb1 = B + (size_t)(n0 + 64 + lrow) * K_DIM + lcol;

    char* lAs = (char*)As;
    char* lBs = (char*)Bs;
    const int wb = wave * 1024;       // 64 lanes * 16 B per wave issue

    i32x4 acc[4][4];
#pragma unroll
    for (int i = 0; i < 4; i++)
#pragma unroll
        for (int j = 0; j < 4; j++) acc[i][j] = (i32x4)(0);

    for (int k0 = 0; k0 < K_DIM; k0 += 64) {
        direct_load16(ga0, lAs + wb);
        direct_load16(ga1, lAs + 4096 + wb);
        direct_load16(gb0, lBs + wb);
        direct_load16(gb1, lBs + 4096 + wb);
        ga0 += 64; ga1 += 64; gb0 += 64; gb1 += 64;
        __syncthreads();              // drains vmcnt -> staged data visible

        i32x4 af[4], bf[4];
#pragma unroll
        for (int i = 0; i < 4; i++)
            af[i] = *(const i32x4*)&As[(wm * 64 + i * 16 + r16) * 64 + quad * 16];
#pragma unroll
        for (int j = 0; j < 4; j++)
            bf[j] = *(const i32x4*)&Bs[(wn * 64 + j * 16 + r16) * 64 + quad * 16];

#pragma unroll
        for (int i = 0; i < 4; i++)
#pragma unroll
            for (int j = 0; j < 4; j++)
                acc[i][j] = __builtin_amdgcn_mfma_i32_16x16x64_i8(af[i], bf[j], acc[i][j], 0, 0, 0);

        __syncthreads();
    }

    // epilogue: fp32 rescale by xs[m]*ws[n]
    float rs[4][4];                   // xs for the 16 m-rows this lane writes
#pragma unroll
    for (int i = 0; i < 4; i++) {
        const int mrow = m0 + wm * 64 + i * 16 + quad * 4;
#pragma unroll
        for (int r = 0; r < 4; r++) rs[i][r] = xs[mrow + r];
    }
#pragma unroll
    for (int j = 0; j < 4; j++) {
        const int n = n0 + wn * 64 + j * 16 + r16;
        const float s = ws[n];
#pragma unroll
        for (int i = 0; i < 4; i++) {
            const int mrow = m0 + wm * 64 + i * 16 + quad * 4;
#pragma unroll
            for (int r = 0; r < 4; r++)
                C[(size_t)(mrow + r) * N_DIM + n] = (float)acc[i][j][r] * s * rs[i][r];
        }
    }
}

// ---- launcher ------------------------------------------------------------

extern "C" void kernel_launch(void* const* d_in, const int* in_sizes, int n_in,
                              void* d_out, int out_size, void* d_ws, size_t ws_size,
                              hipStream_t stream) {
    const float* x       = (const float*)d_in[0];   // [4096][4096]
    const int*   w_int   = (const int*)d_in[1];     // [11008][4096]
    const float* w_scale = (const float*)d_in[2];   // [11008]
    float*       out     = (float*)d_out;           // [4096][11008]

    // ws layout: Wq i8 (45,088,768 B) | Xq i8 (16,777,216 B) | xs f32 (16,384 B)
    int8_t* wq = (int8_t*)d_ws;
    int8_t* xq = (int8_t*)((char*)d_ws + (size_t)N_DIM * K_DIM);
    float*  xs = (float*)((char*)d_ws + (size_t)N_DIM * K_DIM + (size_t)M_DIM * K_DIM);

    // W: 45,088,768 / 8 per thread / 256 = 22016 blocks
    cvt_w_kernel<<<dim3(22016), dim3(256), 0, stream>>>(w_int, wq);
    // x: one block per row
    quant_x_kernel<<<dim3(M_DIM), dim3(256), 0, stream>>>(x, xq, xs);
    // GEMM: (M/128, N/128) = (32, 86)
    gemm_i8_kernel<<<dim3(M_DIM / 128, N_DIM / 128), dim3(256), 0, stream>>>(xq, wq, xs, w_scale, out);
}

// Round 3
// 588.561 us; speedup vs baseline: 1.3361x; 1.0522x over previous
//
#include <hip/hip_runtime.h>
#include <hip/hip_bf16.h>
#include <stdint.h>

// QuantizedLinear: x[8,512,4096] fp32, W[11008,4096] int8-in-int32, scale[11008] fp32
#define M_DIM 4096
#define N_DIM 11008
#define K_DIM 4096

typedef int i32x4 __attribute__((ext_vector_type(4)));

// async global->LDS, 16 bytes/lane. LDS dest = wave-uniform base + lane*16.
static __device__ __forceinline__ void direct_load16(const void* gptr, void* ldsptr) {
    __builtin_amdgcn_global_load_lds(
        (const __attribute__((address_space(1))) void*)gptr,
        (__attribute__((address_space(3))) void*)ldsptr,
        16, 0, 0);
}

// ---- W: int32 in [-127,127] -> int8, 8 elems/thread, coalesced ----------
__global__ __launch_bounds__(256) void cvt_w_kernel(const int* __restrict__ w,
                                                    int8_t* __restrict__ o) {
    int t = blockIdx.x * 256 + threadIdx.x;
    const int4* w4 = (const int4*)w;
    int4 a = w4[2 * t];
    int4 b = w4[2 * t + 1];
    uint2 r;
    r.x = (a.x & 255) | ((a.y & 255) << 8) | ((a.z & 255) << 16) | (a.w << 24);
    r.y = (b.x & 255) | ((b.y & 255) << 8) | ((b.z & 255) << 16) | (b.w << 24);
    ((uint2*)o)[t] = r;
}

// ---- x: fp32 -> int8 with per-row absmax scale --------------------------
__global__ __launch_bounds__(256) void quant_x_kernel(const float* __restrict__ x,
                                                      int8_t* __restrict__ xq,
                                                      float* __restrict__ xs) {
    __shared__ float wmax[4];
    const int row = blockIdx.x;
    const int t = threadIdx.x;
    const float4* xr = (const float4*)(x + (size_t)row * K_DIM);

    float4 v[4];
    float am = 0.0f;
#pragma unroll
    for (int p = 0; p < 4; p++) {
        v[p] = xr[p * 256 + t];
        am = fmaxf(am, fmaxf(fmaxf(fabsf(v[p].x), fabsf(v[p].y)),
                             fmaxf(fabsf(v[p].z), fabsf(v[p].w))));
    }
#pragma unroll
    for (int o = 32; o > 0; o >>= 1)
        am = fmaxf(am, __shfl_xor(am, o));
    if ((t & 63) == 0) wmax[t >> 6] = am;
    __syncthreads();
    am = fmaxf(fmaxf(wmax[0], wmax[1]), fmaxf(wmax[2], wmax[3]));

    const float inv = 127.0f / am;
    int* oq = (int*)(xq + (size_t)row * K_DIM);
#pragma unroll
    for (int p = 0; p < 4; p++) {
        int qa = (int)rintf(v[p].x * inv);
        int qb = (int)rintf(v[p].y * inv);
        int qc = (int)rintf(v[p].z * inv);
        int qd = (int)rintf(v[p].w * inv);
        oq[p * 256 + t] = (qa & 255) | ((qb & 255) << 8) | ((qc & 255) << 16) | (qd << 24);
    }
    if (t == 0) xs[row] = am * (1.0f / 127.0f);
}

// ---- GEMM: C = (Aq . Bq^T) * xs[m] * ws[n] ------------------------------
// 128x128 tile, BK=128 int8 (halves barrier count vs BK=64), XOR-swizzled
// LDS chunks to kill the stride-128B bank pathology. 256 thr = 4 waves (2x2),
// wave: 4x4 of mfma_i32_16x16x64_i8 over 2 k-steps per staged tile.

__global__ __launch_bounds__(256) void gemm_i8_kernel(
    const int8_t* __restrict__ A,     // [M][K] i8
    const int8_t* __restrict__ B,     // [N][K] i8
    const float* __restrict__ xs,     // [M]
    const float* __restrict__ ws,     // [N]
    float* __restrict__ C)            // [M][N] fp32
{
    __shared__ __align__(16) int8_t As[128 * 128];  // [128 rows][8 chunks of 16B], chunk XOR (row&7)
    __shared__ __align__(16) int8_t Bs[128 * 128];

    const int tid  = threadIdx.x;
    const int lane = tid & 63;
    const int wave = tid >> 6;
    const int wm   = wave >> 1;
    const int wn   = wave & 1;
    const int quad = lane >> 4;
    const int r16  = lane & 15;
    const int sw   = r16 & 7;          // read-side swizzle key

    const int m0 = blockIdx.x * 128;   // m fastest -> consecutive blocks share B tile in L2
    const int n0 = blockIdx.y * 128;

    // staging: instruction p covers rows p*32..p*32+31 (32 rows x 128B = 4KB).
    // thread t -> row p*32 + (t>>3), LDS chunk slot (t&7); source col is the
    // XOR-swizzled chunk, so slot (t&7) holds global chunk (t&7)^(row&7).
    const int srow = tid >> 3;                          // 0..31
    const int scol = ((tid & 7) ^ (srow & 7)) * 16;     // swizzled source byte col
    const int8_t* gA = A + (size_t)(m0 + srow) * K_DIM + scol;
    const int8_t* gB = B + (size_t)(n0 + srow) * K_DIM + scol;

    char* lAs = (char*)As;
    char* lBs = (char*)Bs;
    const int wb = wave * 1024;        // lane*16 spans 1KB per wave instruction

    i32x4 acc[4][4];
#pragma unroll
    for (int i = 0; i < 4; i++)
#pragma unroll
        for (int j = 0; j < 4; j++) acc[i][j] = (i32x4)(0);

    for (int k0 = 0; k0 < K_DIM; k0 += 128) {
#pragma unroll
        for (int p = 0; p < 4; p++) {
            direct_load16(gA + (size_t)(p * 32) * K_DIM, lAs + p * 4096 + wb);
            direct_load16(gB + (size_t)(p * 32) * K_DIM, lBs + p * 4096 + wb);
        }
        gA += 128; gB += 128;
        __syncthreads();               // drains vmcnt -> staged data visible

#pragma unroll
        for (int s = 0; s < 2; s++) {
            i32x4 af[4], bf[4];
#pragma unroll
            for (int i = 0; i < 4; i++) {
                const int arow = wm * 64 + i * 16 + r16;
                af[i] = *(const i32x4*)&As[arow * 128 + ((s * 4 + quad) ^ sw) * 16];
            }
#pragma unroll
            for (int j = 0; j < 4; j++) {
                const int brow = wn * 64 + j * 16 + r16;
                bf[j] = *(const i32x4*)&Bs[brow * 128 + ((s * 4 + quad) ^ sw) * 16];
            }
#pragma unroll
            for (int i = 0; i < 4; i++)
#pragma unroll
                for (int j = 0; j < 4; j++)
                    acc[i][j] = __builtin_amdgcn_mfma_i32_16x16x64_i8(af[i], bf[j], acc[i][j], 0, 0, 0);
        }

        __syncthreads();
    }

    // epilogue: fp32 rescale by xs[m]*ws[n]
    float rs[4][4];
#pragma unroll
    for (int i = 0; i < 4; i++) {
        const int mrow = m0 + wm * 64 + i * 16 + quad * 4;
#pragma unroll
        for (int r = 0; r < 4; r++) rs[i][r] = xs[mrow + r];
    }
#pragma unroll
    for (int j = 0; j < 4; j++) {
        const int n = n0 + wn * 64 + j * 16 + r16;
        const float s = ws[n];
#pragma unroll
        for (int i = 0; i < 4; i++) {
            const int mrow = m0 + wm * 64 + i * 16 + quad * 4;
#pragma unroll
            for (int r = 0; r < 4; r++)
                C[(size_t)(mrow + r) * N_DIM + n] = (float)acc[i][j][r] * s * rs[i][r];
        }
    }
}

// ---- launcher ------------------------------------------------------------

extern "C" void kernel_launch(void* const* d_in, const int* in_sizes, int n_in,
                              void* d_out, int out_size, void* d_ws, size_t ws_size,
                              hipStream_t stream) {
    const float* x       = (const float*)d_in[0];   // [4096][4096]
    const int*   w_int   = (const int*)d_in[1];     // [11008][4096]
    const float* w_scale = (const float*)d_in[2];   // [11008]
    float*       out     = (float*)d_out;           // [4096][11008]

    // ws layout: Wq i8 (45,088,768 B) | Xq i8 (16,777,216 B) | xs f32 (16,384 B)
    int8_t* wq = (int8_t*)d_ws;
    int8_t* xq = (int8_t*)((char*)d_ws + (size_t)N_DIM * K_DIM);
    float*  xs = (float*)((char*)d_ws + (size_t)N_DIM * K_DIM + (size_t)M_DIM * K_DIM);

    cvt_w_kernel<<<dim3(22016), dim3(256), 0, stream>>>(w_int, wq);
    quant_x_kernel<<<dim3(M_DIM), dim3(256), 0, stream>>>(x, xq, xs);
    gemm_i8_kernel<<<dim3(M_DIM / 128, N_DIM / 128), dim3(256), 0, stream>>>(xq, wq, xs, w_scale, out);
}